// Round 6
// baseline (300.749 us; speedup 1.0000x reference)
//
#include <hip/hip_runtime.h>

// B=4, S=512, HID=1024, H=16, D=64, NREL=64
// ws: qb bf16(B,H,S,D) | kb bf16(B,H,S,D) | vt bf16(B,H,D,S) | attn_b bf16(B*S,HID)
//     Xq,Xk,Xv bf16 | Wqb,Wkb,Wvb,Wob bf16

typedef __attribute__((ext_vector_type(8))) short bf16x8 __attribute__((may_alias));
typedef __attribute__((ext_vector_type(4))) float f32x4;

__device__ __forceinline__ short f2bf(float x) {
    unsigned u = __float_as_uint(x);
    u += 0x7fff + ((u >> 16) & 1);          // RNE; finite inputs
    return (short)(u >> 16);
}

__device__ __forceinline__ void async16(void* lds, const void* g) {
    __builtin_amdgcn_global_load_lds(
        (const __attribute__((address_space(1))) void*)g,
        (__attribute__((address_space(3))) void*)lds, 16, 0, 0);
}

// ---------- fused fp32 -> bf16 cast of 3 X (2M ea) + 4 W (1M ea) ----------
__global__ __launch_bounds__(256)
void cast_all(const float* __restrict__ x0, const float* __restrict__ x1, const float* __restrict__ x2,
              const float* __restrict__ w0, const float* __restrict__ w1,
              const float* __restrict__ w2, const float* __restrict__ w3,
              short* __restrict__ y0, short* __restrict__ y1, short* __restrict__ y2,
              short* __restrict__ u0, short* __restrict__ u1,
              short* __restrict__ u2, short* __restrict__ u3)
{
    size_t i = (size_t)blockIdx.x * 256 + threadIdx.x;
    const float* src; short* dst; size_t off;
    if (i < 3u*524288u) {
        int s = (int)(i / 524288u); off = i % 524288u;
        src = s == 0 ? x0 : (s == 1 ? x1 : x2);
        dst = s == 0 ? y0 : (s == 1 ? y1 : y2);
    } else {
        size_t j = i - 3u*524288u;
        int s = (int)(j / 262144u); off = j % 262144u;
        src = s == 0 ? w0 : (s == 1 ? w1 : (s == 2 ? w2 : w3));
        dst = s == 0 ? u0 : (s == 1 ? u1 : (s == 2 ? u2 : u3));
    }
    float4 f = ((const float4*)src)[off];
    short4 o; o.x = f2bf(f.x); o.y = f2bf(f.y); o.z = f2bf(f.z); o.w = f2bf(f.w);
    ((short4*)dst)[off] = o;
}

// ---------- bf16 MFMA GEMM (m97 structure): O = A @ B^T + bias ----------
// Tile 128x128, BK=64, 4 waves in 2x2; wave does 64x64 (4x4 MFMA tiles).
// mode 0: O fp32 flat (M,1024). mode 1: O bf16; z<2 -> (b,h,s,d); z==2 -> (b,h,d,s).
// Both bf16 epilogues go through an LDS transpose for 16B coalesced stores.
__global__ __launch_bounds__(256)
void gemm128(const short* __restrict__ A0, const short* __restrict__ A1, const short* __restrict__ A2,
             const short* __restrict__ B0, const short* __restrict__ B1, const short* __restrict__ B2,
             const float* __restrict__ c0, const float* __restrict__ c1, const float* __restrict__ c2,
             void* __restrict__ O0, void* __restrict__ O1, void* __restrict__ O2,
             int mode)
{
    __shared__ short ldsw[128 * 136];        // staging: Als[128*64]|Bls[128*64]; epilogue: Tls[128][136]
    short* Als = ldsw;
    short* Bls = ldsw + 128 * 64;

    const int z = blockIdx.z;
    const short* A    = z == 0 ? A0 : (z == 1 ? A1 : A2);
    const short* Bm   = z == 0 ? B0 : (z == 1 ? B1 : B2);
    const float* bias = z == 0 ? c0 : (z == 1 ? c1 : c2);
    void*        O    = z == 0 ? O0 : (z == 1 ? O1 : O2);

    const int t = threadIdx.x;
    const int lane = t & 63, w = t >> 6;
    const int wr = w >> 1, wc = w & 1;            // wave 2x2 grid
    const int quad = lane >> 4, cl = lane & 15;
    const int rowBase = blockIdx.y * 128;
    const int colBase = blockIdx.x * 128;
    const int gl = ((lane & 7) - (lane >> 3)) & 7;

    f32x4 acc[4][4];
#pragma unroll
    for (int i = 0; i < 4; ++i)
#pragma unroll
        for (int j = 0; j < 4; ++j) acc[i][j] = (f32x4){0.f, 0.f, 0.f, 0.f};

    const int rstage = w * 8 + (lane >> 3);
    const short* Ag = A  + (size_t)(rowBase + rstage) * 1024 + gl * 8;
    const short* Bg = Bm + (size_t)(colBase + rstage) * 1024 + gl * 8;

    for (int it = 0; it < 16; ++it) {
        const int k0 = it * 64;
#pragma unroll
        for (int i = 0; i < 4; ++i)
            async16(&Als[(i * 32 + w * 8) * 64], Ag + (size_t)i * 32 * 1024 + k0);
#pragma unroll
        for (int i = 0; i < 4; ++i)
            async16(&Bls[(i * 32 + w * 8) * 64], Bg + (size_t)i * 32 * 1024 + k0);
        __syncthreads();
#pragma unroll
        for (int kk = 0; kk < 2; ++kk) {
            bf16x8 a[4], b[4];
#pragma unroll
            for (int mi = 0; mi < 4; ++mi) {
                int r = wr * 64 + mi * 16 + cl;
                int s = (kk * 4 + quad + r) & 7;
                a[mi] = *(const bf16x8*)&Als[r * 64 + s * 8];
            }
#pragma unroll
            for (int ni = 0; ni < 4; ++ni) {
                int r = wc * 64 + ni * 16 + cl;
                int s = (kk * 4 + quad + r) & 7;
                b[ni] = *(const bf16x8*)&Bls[r * 64 + s * 8];
            }
#pragma unroll
            for (int mi = 0; mi < 4; ++mi)
#pragma unroll
                for (int ni = 0; ni < 4; ++ni)
                    acc[mi][ni] = __builtin_amdgcn_mfma_f32_16x16x32_bf16(
                        a[mi], b[ni], acc[mi][ni], 0, 0, 0);
        }
        __syncthreads();
    }

    if (mode == 0) {
        // flat f32 (M,1024)
#pragma unroll
        for (int mi = 0; mi < 4; ++mi)
#pragma unroll
            for (int ni = 0; ni < 4; ++ni) {
                int col = colBase + wc * 64 + ni * 16 + cl;
                float bv = bias[col];
#pragma unroll
                for (int reg = 0; reg < 4; ++reg) {
                    int row = rowBase + wr * 64 + mi * 16 + quad * 4 + reg;
                    ((float*)O)[(size_t)row * 1024 + col] = acc[mi][ni][reg] + bv;
                }
            }
        return;
    }

    // bf16 epilogues via LDS transpose. Tls indexed [d_local][s_local] for z==2,
    // [s_local][d_local] for z<2 (write pattern differs, readout coalesced 16B).
    short* Tls = ldsw;   // [128][136]
    if (z == 2) {
        // vt (b,h,d,s): Tls[d][s]
#pragma unroll
        for (int mi = 0; mi < 4; ++mi)
#pragma unroll
            for (int ni = 0; ni < 4; ++ni) {
                int d = wc * 64 + ni * 16 + cl;
                float bv = bias[colBase + d];
                short4 pk;
                pk.x = f2bf(acc[mi][ni][0] + bv);
                pk.y = f2bf(acc[mi][ni][1] + bv);
                pk.z = f2bf(acc[mi][ni][2] + bv);
                pk.w = f2bf(acc[mi][ni][3] + bv);
                int sl = wr * 64 + mi * 16 + quad * 4;
                *(short4*)&Tls[d * 136 + sl] = pk;
            }
        __syncthreads();
        int dl = t >> 4, sl8 = (t & 15) * 8;
        int bb = rowBase >> 9, sBase = rowBase & 511, hh0 = colBase >> 6;
#pragma unroll
        for (int dd = 0; dd < 8; ++dd) {
            int d_local = dd * 16 + dl;
            int hh = hh0 + (d_local >> 6), d = d_local & 63;
            short* dst = (short*)O + (((size_t)(bb * 16 + hh) * 64 + d) << 9) + sBase + sl8;
            *(bf16x8*)dst = *(const bf16x8*)&Tls[d_local * 136 + sl8];
        }
    } else {
        // bhsd: Tls[s][d]
#pragma unroll
        for (int mi = 0; mi < 4; ++mi)
#pragma unroll
            for (int ni = 0; ni < 4; ++ni) {
                int d = wc * 64 + ni * 16 + cl;
                float bv = bias[colBase + d];
#pragma unroll
                for (int reg = 0; reg < 4; ++reg) {
                    int sl = wr * 64 + mi * 16 + quad * 4 + reg;
                    Tls[sl * 136 + d] = f2bf(acc[mi][ni][reg] + bv);
                }
            }
        __syncthreads();
        int sl = t >> 1, half = t & 1;
        int bb = rowBase >> 9, sBase = rowBase & 511, hh = (colBase >> 6) + half;
        short* dst = (short*)O + (((size_t)(bb * 16 + hh) * 512 + sBase + sl) << 6);
#pragma unroll
        for (int j = 0; j < 8; ++j)   // FIX (R5 bug): 8 x bf16x8 = full 64-d head row
            *(bf16x8*)(dst + j * 8) = *(const bf16x8*)&Tls[sl * 136 + half * 64 + j * 8];
    }
}

// ---------------- Attention: barrier-lite, shared accumulators ----------------
// block = (b,h, 16-query tile); wave w owns keys [w*128,(w+1)*128).
// LDS pool (bytes):
//   0      qwr  f32[16][68] (4352)   [post-#1: binsBf short[16][72] aliases]
//   4352   bins f32[16][68] (4352)   shared, ds_add_f32
//   8704   Oacc f32[16][68] (4352)   shared, ds_add_f32
//   13056  Lacc f32[16] + invl f32[16] (128)
//   13184  Pst  4 x short[16][72] (9216) wave-private
#define A_OFF_BINS 4352
#define A_OFF_OACC 8704
#define A_OFF_LACC 13056
#define A_OFF_INVL 13120
#define A_OFF_PST  13184
#define A_LDS_TOT  22400

__global__ __launch_bounds__(256, 6)
void attn_kernel(const short* __restrict__ qg, const short* __restrict__ kg,
                 const short* __restrict__ vtg, const int* __restrict__ mask,
                 const float* __restrict__ relk, const float* __restrict__ relv,
                 short* __restrict__ attn_b)
{
    __shared__ __align__(16) char pool[A_LDS_TOT];
    float* qwr    = (float*)pool;
    short* binsBf = (short*)pool;
    float* bins   = (float*)(pool + A_OFF_BINS);
    float* Oacc   = (float*)(pool + A_OFF_OACC);
    float* Lacc   = (float*)(pool + A_OFF_LACC);
    float* invl   = (float*)(pool + A_OFF_INVL);

    const int t = threadIdx.x, lane = t & 63, w = t >> 6;
    const int quad = lane >> 4, cl = lane & 15;
    const int bid = blockIdx.x, qbk = bid & 31, bh = bid >> 5;
    const int b = bh >> 4, h = bh & 15, q0 = qbk * 16;

    const short* qbase = qg  + ((size_t)bh * 512 + q0) * 64;
    const short* kbase = kg  + (size_t)bh * 512 * 64;
    const short* vbase = vtg + (size_t)bh * 64 * 512;
    const int*   mb    = mask + (size_t)b * 512 * 512 + (size_t)q0 * 512;

    short* Pst = (short*)(pool + A_OFF_PST + w * 2304);

    // zero shared accumulators (bins, Oacc, Lacc, invl)
    for (int i = t; i < (A_OFF_PST - A_OFF_BINS) / 4; i += 256)
        bins[i] = 0.f;

    // prefetch relv B-fragments (n-tile = w)
    bf16x8 rvb0, rvb1;
    {
        const float* rp = relv + (size_t)(quad * 8) * 64 + w * 16 + cl;
#pragma unroll
        for (int j = 0; j < 8; ++j) rvb0[j] = f2bf(rp[j * 64]);
#pragma unroll
        for (int j = 0; j < 8; ++j) rvb1[j] = f2bf(rp[2048 + j * 64]);
    }

    // Q A-fragments direct from global
    bf16x8 qa0 = *(const bf16x8*)(qbase + cl * 64 + quad * 8);
    bf16x8 qa1 = *(const bf16x8*)(qbase + cl * 64 + 32 + quad * 8);

    // qrel: wave w computes r-tile w -> qwr[q][r]
    {
        const float* kp = relk + (size_t)(w * 16 + cl) * 64 + quad * 8;
        bf16x8 rb0, rb1;
#pragma unroll
        for (int j = 0; j < 8; ++j) rb0[j] = f2bf(kp[j]);
#pragma unroll
        for (int j = 0; j < 8; ++j) rb1[j] = f2bf(kp[32 + j]);
        f32x4 qr = (f32x4){0.f, 0.f, 0.f, 0.f};
        qr = __builtin_amdgcn_mfma_f32_16x16x32_bf16(qa0, rb0, qr, 0, 0, 0);
        qr = __builtin_amdgcn_mfma_f32_16x16x32_bf16(qa1, rb1, qr, 0, 0, 0);
#pragma unroll
        for (int reg = 0; reg < 4; ++reg)
            qwr[(quad * 4 + reg) * 68 + w * 16 + cl] = qr[reg];
    }
    __syncthreads();   // #0: qwr + zeroed accumulators visible

    // ---- K-loop: 2 chunks of 64 keys per wave, no barriers ----
    f32x4 oacc[4];
#pragma unroll
    for (int dt = 0; dt < 4; ++dt) oacc[dt] = (f32x4){0.f, 0.f, 0.f, 0.f};
    float lpart[4] = {0.f, 0.f, 0.f, 0.f};

#pragma unroll
    for (int c = 0; c < 2; ++c) {
        const int k0 = w * 128 + c * 64;
        // hoist the 16 mask loads for this chunk
        int idv[4][4];
#pragma unroll
        for (int nt = 0; nt < 4; ++nt)
#pragma unroll
            for (int reg = 0; reg < 4; ++reg)
                idv[nt][reg] = mb[(quad * 4 + reg) * 512 + k0 + nt * 16 + cl];

#pragma unroll
        for (int nt = 0; nt < 4; ++nt) {
            const short* kp = kbase + (size_t)(k0 + nt * 16 + cl) * 64 + quad * 8;
            bf16x8 kb0 = *(const bf16x8*)kp;
            bf16x8 kb1 = *(const bf16x8*)(kp + 32);
            f32x4 s = (f32x4){0.f, 0.f, 0.f, 0.f};
            s = __builtin_amdgcn_mfma_f32_16x16x32_bf16(qa0, kb0, s, 0, 0, 0);
            s = __builtin_amdgcn_mfma_f32_16x16x32_bf16(qa1, kb1, s, 0, 0, 0);
#pragma unroll
            for (int reg = 0; reg < 4; ++reg) {
                int q = quad * 4 + reg;
                int id = idv[nt][reg];
                float sc = (s[reg] + 0.25f * qwr[q * 68 + id]) * 0.125f;
                sc = (id == 0) ? sc - 10000.f : sc;
                float p = __expf(sc);       // no-max softmax: scores bounded
                lpart[reg] += p;
                atomicAdd(&bins[q * 68 + id], p);
                Pst[q * 72 + nt * 16 + cl] = f2bf(p);
            }
        }
        // P C-layout -> A-layout via wave-private LDS (in-wave RAW)
        bf16x8 pa0 = *(const bf16x8*)&Pst[cl * 72 + quad * 8];
        bf16x8 pa1 = *(const bf16x8*)&Pst[cl * 72 + 32 + quad * 8];
#pragma unroll
        for (int dt = 0; dt < 4; ++dt) {
            const short* vp = vbase + (size_t)(dt * 16 + cl) * 512 + k0 + quad * 8;
            bf16x8 vb0 = *(const bf16x8*)vp;
            bf16x8 vb1 = *(const bf16x8*)(vp + 32);
            oacc[dt] = __builtin_amdgcn_mfma_f32_16x16x32_bf16(pa0, vb0, oacc[dt], 0, 0, 0);
            oacc[dt] = __builtin_amdgcn_mfma_f32_16x16x32_bf16(pa1, vb1, oacc[dt], 0, 0, 0);
        }
    }

    // merge into shared accumulators
#pragma unroll
    for (int reg = 0; reg < 4; ++reg) {
        int q = quad * 4 + reg;
#pragma unroll
        for (int dt = 0; dt < 4; ++dt)
            atomicAdd(&Oacc[q * 68 + dt * 16 + cl], oacc[dt][reg]);
        float lsum = lpart[reg];
#pragma unroll
        for (int m = 8; m >= 1; m >>= 1) lsum += __shfl_xor(lsum, m);
        if (cl == 0) atomicAdd(&Lacc[q], lsum);
    }
    __syncthreads();   // #1: Oacc, Lacc, bins complete

    // bins -> bf16 (binsBf aliases dead qwr region), invl
    if (t < 16) invl[t] = 1.0f / Lacc[t];
    {
        int q = t >> 4, r0 = (t & 15) * 4;
        float4 f = *(const float4*)&bins[q * 68 + r0];
        short4 o;
        o.x = f2bf(f.x); o.y = f2bf(f.y); o.z = f2bf(f.z); o.w = f2bf(f.w);
        *(short4*)&binsBf[q * 72 + r0] = o;
    }
    __syncthreads();   // #2

    // rel_out = bins @ relv (wave w -> d-tile w), combine + normalize + store
    bf16x8 ba0 = *(const bf16x8*)&binsBf[cl * 72 + quad * 8];
    bf16x8 ba1 = *(const bf16x8*)&binsBf[cl * 72 + 32 + quad * 8];
    f32x4 racc = (f32x4){0.f, 0.f, 0.f, 0.f};
    racc = __builtin_amdgcn_mfma_f32_16x16x32_bf16(ba0, rvb0, racc, 0, 0, 0);
    racc = __builtin_amdgcn_mfma_f32_16x16x32_bf16(ba1, rvb1, racc, 0, 0, 0);

#pragma unroll
    for (int reg = 0; reg < 4; ++reg) {
        int q = quad * 4 + reg;
        int d = w * 16 + cl;
        float val = (Oacc[q * 68 + d] + 0.25f * racc[reg]) * invl[q];
        attn_b[(size_t)(b * 512 + q0 + q) * 1024 + h * 64 + d] = f2bf(val);
    }
}

extern "C" void kernel_launch(void* const* d_in, const int* in_sizes, int n_in,
                              void* d_out, int out_size, void* d_ws, size_t ws_size,
                              hipStream_t stream)
{
    const float* q_in = (const float*)d_in[0];
    const float* k_in = (const float*)d_in[1];
    const float* v_in = (const float*)d_in[2];
    const int*   mask = (const int*)d_in[3];
    const float* Wq   = (const float*)d_in[4];
    const float* bq   = (const float*)d_in[5];
    const float* Wk   = (const float*)d_in[6];
    const float* bk   = (const float*)d_in[7];
    const float* Wv   = (const float*)d_in[8];
    const float* bv   = (const float*)d_in[9];
    const float* Wo   = (const float*)d_in[10];
    const float* bo   = (const float*)d_in[11];
    const float* relk = (const float*)d_in[12];
    const float* relv = (const float*)d_in[13];

    char* ws = (char*)d_ws;
    short* qb     = (short*)(ws);                  // 4MB
    short* kb     = (short*)(ws + (4u  << 20));    // 4MB
    short* vt     = (short*)(ws + (8u  << 20));    // 4MB
    short* attn_b = (short*)(ws + (12u << 20));    // 4MB
    short* Xq     = (short*)(ws + (16u << 20));    // 4MB
    short* Xk     = (short*)(ws + (20u << 20));
    short* Xv     = (short*)(ws + (24u << 20));
    short* Wqb    = (short*)(ws + (28u << 20));    // 2MB
    short* Wkb    = (short*)(ws + (30u << 20));
    short* Wvb    = (short*)(ws + (32u << 20));
    short* Wob    = (short*)(ws + (34u << 20));

    cast_all<<<10240, 256, 0, stream>>>(q_in, k_in, v_in, Wq, Wk, Wv, Wo,
                                        Xq, Xk, Xv, Wqb, Wkb, Wvb, Wob);

    gemm128<<<dim3(8, 16, 3), 256, 0, stream>>>(
        Xq, Xk, Xv, Wqb, Wkb, Wvb, bq, bk, bv, qb, kb, vt, 1);

    attn_kernel<<<dim3(2048), 256, 0, stream>>>(qb, kb, vt, mask, relk, relv, attn_b);

    gemm128<<<dim3(8, 16, 1), 256, 0, stream>>>(
        attn_b, attn_b, attn_b, Wob, Wob, Wob, bo, bo, bo,
        (void*)d_out, (void*)d_out, (void*)d_out, 0);
}

// Round 7
// 279.580 us; speedup vs baseline: 1.0757x; 1.0757x over previous
//
#include <hip/hip_runtime.h>

// B=4, S=512, HID=1024, H=16, D=64, NREL=64
// ws: qb bf16(B,H,S,D) | kb bf16(B,H,S,D) | vt bf16(B,H,D,S) | attn_b bf16(B*S,HID)
//     Xq,Xk,Xv bf16 | Wqb,Wkb,Wvb,Wob bf16

typedef __attribute__((ext_vector_type(8))) short bf16x8 __attribute__((may_alias));
typedef __attribute__((ext_vector_type(4))) float f32x4;

__device__ __forceinline__ short f2bf(float x) {
    unsigned u = __float_as_uint(x);
    u += 0x7fff + ((u >> 16) & 1);          // RNE; finite inputs
    return (short)(u >> 16);
}

__device__ __forceinline__ void async16(void* lds, const void* g) {
    __builtin_amdgcn_global_load_lds(
        (const __attribute__((address_space(1))) void*)g,
        (__attribute__((address_space(3))) void*)lds, 16, 0, 0);
}

// ---------- fused fp32 -> bf16 cast of 3 X (2M ea) + 4 W (1M ea) ----------
__global__ __launch_bounds__(256)
void cast_all(const float* __restrict__ x0, const float* __restrict__ x1, const float* __restrict__ x2,
              const float* __restrict__ w0, const float* __restrict__ w1,
              const float* __restrict__ w2, const float* __restrict__ w3,
              short* __restrict__ y0, short* __restrict__ y1, short* __restrict__ y2,
              short* __restrict__ u0, short* __restrict__ u1,
              short* __restrict__ u2, short* __restrict__ u3)
{
    size_t i = (size_t)blockIdx.x * 256 + threadIdx.x;
    const float* src; short* dst; size_t off;
    if (i < 3u*524288u) {
        int s = (int)(i / 524288u); off = i % 524288u;
        src = s == 0 ? x0 : (s == 1 ? x1 : x2);
        dst = s == 0 ? y0 : (s == 1 ? y1 : y2);
    } else {
        size_t j = i - 3u*524288u;
        int s = (int)(j / 262144u); off = j % 262144u;
        src = s == 0 ? w0 : (s == 1 ? w1 : (s == 2 ? w2 : w3));
        dst = s == 0 ? u0 : (s == 1 ? u1 : (s == 2 ? u2 : u3));
    }
    float4 f = ((const float4*)src)[off];
    short4 o; o.x = f2bf(f.x); o.y = f2bf(f.y); o.z = f2bf(f.z); o.w = f2bf(f.w);
    ((short4*)dst)[off] = o;
}

// ---------- bf16 MFMA GEMM (m97 structure + LDS double-buffer): O = A @ B^T + bias ----------
// Tile 128x128, BK=64, 4 waves in 2x2; wave does 64x64 (4x4 MFMA tiles).
// Double-buffered staging: loads for tile it+1 issued right after the barrier that
// publishes tile it; the NEXT barrier's vmcnt(0) drain completes them. 1 barrier/iter.
// mode 0: O fp32 flat (M,1024). mode 1: O bf16; z<2 -> (b,h,s,d); z==2 -> (b,h,d,s).
__global__ __launch_bounds__(256)
void gemm128(const short* __restrict__ A0, const short* __restrict__ A1, const short* __restrict__ A2,
             const short* __restrict__ B0, const short* __restrict__ B1, const short* __restrict__ B2,
             const float* __restrict__ c0, const float* __restrict__ c1, const float* __restrict__ c2,
             void* __restrict__ O0, void* __restrict__ O1, void* __restrict__ O2,
             int mode)
{
    __shared__ short ldsw[4 * 8192];         // [buf][A|B][128*64]; epilogue reuses as Tls[128][136]

    const int z = blockIdx.z;
    const short* A    = z == 0 ? A0 : (z == 1 ? A1 : A2);
    const short* Bm   = z == 0 ? B0 : (z == 1 ? B1 : B2);
    const float* bias = z == 0 ? c0 : (z == 1 ? c1 : c2);
    void*        O    = z == 0 ? O0 : (z == 1 ? O1 : O2);

    const int t = threadIdx.x;
    const int lane = t & 63, w = t >> 6;
    const int wr = w >> 1, wc = w & 1;            // wave 2x2 grid
    const int quad = lane >> 4, cl = lane & 15;
    const int rowBase = blockIdx.y * 128;
    const int colBase = blockIdx.x * 128;
    const int gl = ((lane & 7) - (lane >> 3)) & 7;

    f32x4 acc[4][4];
#pragma unroll
    for (int i = 0; i < 4; ++i)
#pragma unroll
        for (int j = 0; j < 4; ++j) acc[i][j] = (f32x4){0.f, 0.f, 0.f, 0.f};

    const int rstage = w * 8 + (lane >> 3);
    const short* Ag = A  + (size_t)(rowBase + rstage) * 1024 + gl * 8;
    const short* Bg = Bm + (size_t)(colBase + rstage) * 1024 + gl * 8;

    // prologue: stage tile 0 into buf 0
    {
        short* Als = ldsw;
        short* Bls = ldsw + 8192;
#pragma unroll
        for (int i = 0; i < 4; ++i)
            async16(&Als[(i * 32 + w * 8) * 64], Ag + (size_t)i * 32 * 1024);
#pragma unroll
        for (int i = 0; i < 4; ++i)
            async16(&Bls[(i * 32 + w * 8) * 64], Bg + (size_t)i * 32 * 1024);
    }

    for (int it = 0; it < 16; ++it) {
        const int cur = it & 1;
        __syncthreads();                          // drains vmcnt -> buf[cur] valid
        if (it < 15) {
            short* Als = ldsw + (cur ^ 1) * 16384;
            short* Bls = Als + 8192;
            const int k0 = (it + 1) * 64;
#pragma unroll
            for (int i = 0; i < 4; ++i)
                async16(&Als[(i * 32 + w * 8) * 64], Ag + (size_t)i * 32 * 1024 + k0);
#pragma unroll
            for (int i = 0; i < 4; ++i)
                async16(&Bls[(i * 32 + w * 8) * 64], Bg + (size_t)i * 32 * 1024 + k0);
        }
        const short* Als = ldsw + cur * 16384;
        const short* Bls = Als + 8192;
#pragma unroll
        for (int kk = 0; kk < 2; ++kk) {
            bf16x8 a[4], b[4];
#pragma unroll
            for (int mi = 0; mi < 4; ++mi) {
                int r = wr * 64 + mi * 16 + cl;
                int s = (kk * 4 + quad + r) & 7;
                a[mi] = *(const bf16x8*)&Als[r * 64 + s * 8];
            }
#pragma unroll
            for (int ni = 0; ni < 4; ++ni) {
                int r = wc * 64 + ni * 16 + cl;
                int s = (kk * 4 + quad + r) & 7;
                b[ni] = *(const bf16x8*)&Bls[r * 64 + s * 8];
            }
#pragma unroll
            for (int mi = 0; mi < 4; ++mi)
#pragma unroll
                for (int ni = 0; ni < 4; ++ni)
                    acc[mi][ni] = __builtin_amdgcn_mfma_f32_16x16x32_bf16(
                        a[mi], b[ni], acc[mi][ni], 0, 0, 0);
        }
    }

    if (mode == 0) {
        // flat f32 (M,1024)
#pragma unroll
        for (int mi = 0; mi < 4; ++mi)
#pragma unroll
            for (int ni = 0; ni < 4; ++ni) {
                int col = colBase + wc * 64 + ni * 16 + cl;
                float bv = bias[col];
#pragma unroll
                for (int reg = 0; reg < 4; ++reg) {
                    int row = rowBase + wr * 64 + mi * 16 + quad * 4 + reg;
                    ((float*)O)[(size_t)row * 1024 + col] = acc[mi][ni][reg] + bv;
                }
            }
        return;
    }

    __syncthreads();                              // all reads of staging done before Tls reuse
    short* Tls = ldsw;   // [128][136]
    if (z == 2) {
        // vt (b,h,d,s): Tls[d][s]
#pragma unroll
        for (int mi = 0; mi < 4; ++mi)
#pragma unroll
            for (int ni = 0; ni < 4; ++ni) {
                int d = wc * 64 + ni * 16 + cl;
                float bv = bias[colBase + d];
                short4 pk;
                pk.x = f2bf(acc[mi][ni][0] + bv);
                pk.y = f2bf(acc[mi][ni][1] + bv);
                pk.z = f2bf(acc[mi][ni][2] + bv);
                pk.w = f2bf(acc[mi][ni][3] + bv);
                int sl = wr * 64 + mi * 16 + quad * 4;
                *(short4*)&Tls[d * 136 + sl] = pk;
            }
        __syncthreads();
        int dl = t >> 4, sl8 = (t & 15) * 8;
        int bb = rowBase >> 9, sBase = rowBase & 511, hh0 = colBase >> 6;
#pragma unroll
        for (int dd = 0; dd < 8; ++dd) {
            int d_local = dd * 16 + dl;
            int hh = hh0 + (d_local >> 6), d = d_local & 63;
            short* dst = (short*)O + (((size_t)(bb * 16 + hh) * 64 + d) << 9) + sBase + sl8;
            *(bf16x8*)dst = *(const bf16x8*)&Tls[d_local * 136 + sl8];
        }
    } else {
        // bhsd: Tls[s][d]
#pragma unroll
        for (int mi = 0; mi < 4; ++mi)
#pragma unroll
            for (int ni = 0; ni < 4; ++ni) {
                int d = wc * 64 + ni * 16 + cl;
                float bv = bias[colBase + d];
#pragma unroll
                for (int reg = 0; reg < 4; ++reg) {
                    int sl = wr * 64 + mi * 16 + quad * 4 + reg;
                    Tls[sl * 136 + d] = f2bf(acc[mi][ni][reg] + bv);
                }
            }
        __syncthreads();
        int sl = t >> 1, half = t & 1;
        int bb = rowBase >> 9, sBase = rowBase & 511, hh = (colBase >> 6) + half;
        short* dst = (short*)O + (((size_t)(bb * 16 + hh) * 512 + sBase + sl) << 6);
#pragma unroll
        for (int j = 0; j < 8; ++j)   // 8 x bf16x8 = full 64-d head row
            *(bf16x8*)(dst + j * 8) = *(const bf16x8*)&Tls[sl * 136 + half * 64 + j * 8];
    }
}

// ---------------- Attention: barrier-lite, shared accumulators ----------------
// block = (b,h, 16-query tile); wave w owns keys [w*128,(w+1)*128).
// LDS pool (bytes):
//   0      qwr  f32[16][68] (4352)   [post-#1: binsBf short[16][72] aliases]
//   4352   bins f32[16][68] (4352)   shared, ds atomics
//   8704   Oacc f32[16][68] (4352)   shared, ds atomics
//   13056  Lacc f32[16] + invl f32[16] (128)
//   13184  Pst  4 x short[16][72] (9216) wave-private
// NOTE: no min-waves clause — R6's (256,6) capped VGPRs at ~85 and the hoisted
// mask regs pushed demand over it -> scratch spills -> 78 MB of HBM writes.
#define A_OFF_BINS 4352
#define A_OFF_OACC 8704
#define A_OFF_LACC 13056
#define A_OFF_INVL 13120
#define A_OFF_PST  13184
#define A_LDS_TOT  22400

__global__ __launch_bounds__(256)
void attn_kernel(const short* __restrict__ qg, const short* __restrict__ kg,
                 const short* __restrict__ vtg, const int* __restrict__ mask,
                 const float* __restrict__ relk, const float* __restrict__ relv,
                 short* __restrict__ attn_b)
{
    __shared__ __align__(16) char pool[A_LDS_TOT];
    float* qwr    = (float*)pool;
    short* binsBf = (short*)pool;
    float* bins   = (float*)(pool + A_OFF_BINS);
    float* Oacc   = (float*)(pool + A_OFF_OACC);
    float* Lacc   = (float*)(pool + A_OFF_LACC);
    float* invl   = (float*)(pool + A_OFF_INVL);

    const int t = threadIdx.x, lane = t & 63, w = t >> 6;
    const int quad = lane >> 4, cl = lane & 15;
    const int bid = blockIdx.x, qbk = bid & 31, bh = bid >> 5;
    const int b = bh >> 4, h = bh & 15, q0 = qbk * 16;

    const short* qbase = qg  + ((size_t)bh * 512 + q0) * 64;
    const short* kbase = kg  + (size_t)bh * 512 * 64;
    const short* vbase = vtg + (size_t)bh * 64 * 512;
    const int*   mb    = mask + (size_t)b * 512 * 512 + (size_t)q0 * 512;

    short* Pst = (short*)(pool + A_OFF_PST + w * 2304);

    // zero shared accumulators (bins, Oacc, Lacc, invl)
    for (int i = t; i < (A_OFF_PST - A_OFF_BINS) / 4; i += 256)
        bins[i] = 0.f;

    // prefetch relv B-fragments (n-tile = w)
    bf16x8 rvb0, rvb1;
    {
        const float* rp = relv + (size_t)(quad * 8) * 64 + w * 16 + cl;
#pragma unroll
        for (int j = 0; j < 8; ++j) rvb0[j] = f2bf(rp[j * 64]);
#pragma unroll
        for (int j = 0; j < 8; ++j) rvb1[j] = f2bf(rp[2048 + j * 64]);
    }

    // Q A-fragments direct from global
    bf16x8 qa0 = *(const bf16x8*)(qbase + cl * 64 + quad * 8);
    bf16x8 qa1 = *(const bf16x8*)(qbase + cl * 64 + 32 + quad * 8);

    // qrel: wave w computes r-tile w -> qwr[q][r]
    {
        const float* kp = relk + (size_t)(w * 16 + cl) * 64 + quad * 8;
        bf16x8 rb0, rb1;
#pragma unroll
        for (int j = 0; j < 8; ++j) rb0[j] = f2bf(kp[j]);
#pragma unroll
        for (int j = 0; j < 8; ++j) rb1[j] = f2bf(kp[32 + j]);
        f32x4 qr = (f32x4){0.f, 0.f, 0.f, 0.f};
        qr = __builtin_amdgcn_mfma_f32_16x16x32_bf16(qa0, rb0, qr, 0, 0, 0);
        qr = __builtin_amdgcn_mfma_f32_16x16x32_bf16(qa1, rb1, qr, 0, 0, 0);
#pragma unroll
        for (int reg = 0; reg < 4; ++reg)
            qwr[(quad * 4 + reg) * 68 + w * 16 + cl] = qr[reg];
    }
    __syncthreads();   // #0: qwr + zeroed accumulators visible

    // ---- K-loop: 2 chunks of 64 keys per wave, no barriers ----
    f32x4 oacc[4];
#pragma unroll
    for (int dt = 0; dt < 4; ++dt) oacc[dt] = (f32x4){0.f, 0.f, 0.f, 0.f};
    float lpart[4] = {0.f, 0.f, 0.f, 0.f};

#pragma unroll
    for (int c = 0; c < 2; ++c) {
        const int k0 = w * 128 + c * 64;
#pragma unroll
        for (int nt = 0; nt < 4; ++nt) {
            const int kidx = k0 + nt * 16 + cl;
            const short* kp = kbase + (size_t)kidx * 64 + quad * 8;
            bf16x8 kb0 = *(const bf16x8*)kp;
            bf16x8 kb1 = *(const bf16x8*)(kp + 32);
            f32x4 s = (f32x4){0.f, 0.f, 0.f, 0.f};
            s = __builtin_amdgcn_mfma_f32_16x16x32_bf16(qa0, kb0, s, 0, 0, 0);
            s = __builtin_amdgcn_mfma_f32_16x16x32_bf16(qa1, kb1, s, 0, 0, 0);
#pragma unroll
            for (int reg = 0; reg < 4; ++reg) {
                int q = quad * 4 + reg;
                int id = mb[q * 512 + kidx];          // per-nt loads: keep VGPR pressure low
                float sc = (s[reg] + 0.25f * qwr[q * 68 + id]) * 0.125f;
                sc = (id == 0) ? sc - 10000.f : sc;
                float p = __expf(sc);                 // no-max softmax: scores bounded
                lpart[reg] += p;
                atomicAdd(&bins[q * 68 + id], p);
                Pst[q * 72 + nt * 16 + cl] = f2bf(p);
            }
        }
        // P C-layout -> A-layout via wave-private LDS (in-wave RAW)
        bf16x8 pa0 = *(const bf16x8*)&Pst[cl * 72 + quad * 8];
        bf16x8 pa1 = *(const bf16x8*)&Pst[cl * 72 + 32 + quad * 8];
#pragma unroll
        for (int dt = 0; dt < 4; ++dt) {
            const short* vp = vbase + (size_t)(dt * 16 + cl) * 512 + k0 + quad * 8;
            bf16x8 vb0 = *(const bf16x8*)vp;
            bf16x8 vb1 = *(const bf16x8*)(vp + 32);
            oacc[dt] = __builtin_amdgcn_mfma_f32_16x16x32_bf16(pa0, vb0, oacc[dt], 0, 0, 0);
            oacc[dt] = __builtin_amdgcn_mfma_f32_16x16x32_bf16(pa1, vb1, oacc[dt], 0, 0, 0);
        }
    }

    // merge into shared accumulators
#pragma unroll
    for (int reg = 0; reg < 4; ++reg) {
        int q = quad * 4 + reg;
#pragma unroll
        for (int dt = 0; dt < 4; ++dt)
            atomicAdd(&Oacc[q * 68 + dt * 16 + cl], oacc[dt][reg]);
        float lsum = lpart[reg];
#pragma unroll
        for (int m = 8; m >= 1; m >>= 1) lsum += __shfl_xor(lsum, m);
        if (cl == 0) atomicAdd(&Lacc[q], lsum);
    }
    __syncthreads();   // #1: Oacc, Lacc, bins complete

    // bins -> bf16 (binsBf aliases dead qwr region), invl
    if (t < 16) invl[t] = 1.0f / Lacc[t];
    {
        int q = t >> 4, r0 = (t & 15) * 4;
        float4 f = *(const float4*)&bins[q * 68 + r0];
        short4 o;
        o.x = f2bf(f.x); o.y = f2bf(f.y); o.z = f2bf(f.z); o.w = f2bf(f.w);
        *(short4*)&binsBf[q * 72 + r0] = o;
    }
    __syncthreads();   // #2

    // rel_out = bins @ relv (wave w -> d-tile w), combine + normalize + store
    bf16x8 ba0 = *(const bf16x8*)&binsBf[cl * 72 + quad * 8];
    bf16x8 ba1 = *(const bf16x8*)&binsBf[cl * 72 + 32 + quad * 8];
    f32x4 racc = (f32x4){0.f, 0.f, 0.f, 0.f};
    racc = __builtin_amdgcn_mfma_f32_16x16x32_bf16(ba0, rvb0, racc, 0, 0, 0);
    racc = __builtin_amdgcn_mfma_f32_16x16x32_bf16(ba1, rvb1, racc, 0, 0, 0);

#pragma unroll
    for (int reg = 0; reg < 4; ++reg) {
        int q = quad * 4 + reg;
        int d = w * 16 + cl;
        float val = (Oacc[q * 68 + d] + 0.25f * racc[reg]) * invl[q];
        attn_b[(size_t)(b * 512 + q0 + q) * 1024 + h * 64 + d] = f2bf(val);
    }
}

extern "C" void kernel_launch(void* const* d_in, const int* in_sizes, int n_in,
                              void* d_out, int out_size, void* d_ws, size_t ws_size,
                              hipStream_t stream)
{
    const float* q_in = (const float*)d_in[0];
    const float* k_in = (const float*)d_in[1];
    const float* v_in = (const float*)d_in[2];
    const int*   mask = (const int*)d_in[3];
    const float* Wq   = (const float*)d_in[4];
    const float* bq   = (const float*)d_in[5];
    const float* Wk   = (const float*)d_in[6];
    const float* bk   = (const float*)d_in[7];
    const float* Wv   = (const float*)d_in[8];
    const float* bv   = (const float*)d_in[9];
    const float* Wo   = (const float*)d_in[10];
    const float* bo   = (const float*)d_in[11];
    const float* relk = (const float*)d_in[12];
    const float* relv = (const float*)d_in[13];

    char* ws = (char*)d_ws;
    short* qb     = (short*)(ws);                  // 4MB
    short* kb     = (short*)(ws + (4u  << 20));    // 4MB
    short* vt     = (short*)(ws + (8u  << 20));    // 4MB
    short* attn_b = (short*)(ws + (12u << 20));    // 4MB
    short* Xq     = (short*)(ws + (16u << 20));    // 4MB
    short* Xk     = (short*)(ws + (20u << 20));
    short* Xv     = (short*)(ws + (24u << 20));
    short* Wqb    = (short*)(ws + (28u << 20));    // 2MB
    short* Wkb    = (short*)(ws + (30u << 20));
    short* Wvb    = (short*)(ws + (32u << 20));
    short* Wob    = (short*)(ws + (34u << 20));

    cast_all<<<10240, 256, 0, stream>>>(q_in, k_in, v_in, Wq, Wk, Wv, Wo,
                                        Xq, Xk, Xv, Wqb, Wkb, Wvb, Wob);

    gemm128<<<dim3(8, 16, 3), 256, 0, stream>>>(
        Xq, Xk, Xv, Wqb, Wkb, Wvb, bq, bk, bv, qb, kb, vt, 1);

    attn_kernel<<<dim3(2048), 256, 0, stream>>>(qb, kb, vt, mask, relk, relv, attn_b);

    gemm128<<<dim3(8, 16, 1), 256, 0, stream>>>(
        attn_b, attn_b, attn_b, Wob, Wob, Wob, bo, bo, bo,
        (void*)d_out, (void*)d_out, (void*)d_out, 0);
}

// Round 8
// 238.995 us; speedup vs baseline: 1.2584x; 1.1698x over previous
//
#include <hip/hip_runtime.h>

// B=4, S=512, HID=1024, H=16, D=64, NREL=64
// ws: qb bf16(B,H,S,D) | kb bf16(B,H,S,D) | vt bf16(B,H,D,S) | attn_b bf16(B*S,HID)
//     Xq,Xk,Xv bf16 | Wqb,Wkb,Wvb,Wob bf16

typedef __attribute__((ext_vector_type(8))) short bf16x8 __attribute__((may_alias));
typedef __attribute__((ext_vector_type(4))) float f32x4;

__device__ __forceinline__ short f2bf(float x) {
    unsigned u = __float_as_uint(x);
    u += 0x7fff + ((u >> 16) & 1);          // RNE; finite inputs
    return (short)(u >> 16);
}

__device__ __forceinline__ void async16(void* lds, const void* g) {
    __builtin_amdgcn_global_load_lds(
        (const __attribute__((address_space(1))) void*)g,
        (__attribute__((address_space(3))) void*)lds, 16, 0, 0);
}

// ---------- fused fp32 -> bf16 cast of 3 X (2M ea) + 4 W (1M ea) ----------
__global__ __launch_bounds__(256)
void cast_all(const float* __restrict__ x0, const float* __restrict__ x1, const float* __restrict__ x2,
              const float* __restrict__ w0, const float* __restrict__ w1,
              const float* __restrict__ w2, const float* __restrict__ w3,
              short* __restrict__ y0, short* __restrict__ y1, short* __restrict__ y2,
              short* __restrict__ u0, short* __restrict__ u1,
              short* __restrict__ u2, short* __restrict__ u3)
{
    size_t i = (size_t)blockIdx.x * 256 + threadIdx.x;
    const float* src; short* dst; size_t off;
    if (i < 3u*524288u) {
        int s = (int)(i / 524288u); off = i % 524288u;
        src = s == 0 ? x0 : (s == 1 ? x1 : x2);
        dst = s == 0 ? y0 : (s == 1 ? y1 : y2);
    } else {
        size_t j = i - 3u*524288u;
        int s = (int)(j / 262144u); off = j % 262144u;
        src = s == 0 ? w0 : (s == 1 ? w1 : (s == 2 ? w2 : w3));
        dst = s == 0 ? u0 : (s == 1 ? u1 : (s == 2 ? u2 : u3));
    }
    float4 f = ((const float4*)src)[off];
    short4 o; o.x = f2bf(f.x); o.y = f2bf(f.y); o.z = f2bf(f.z); o.w = f2bf(f.w);
    ((short4*)dst)[off] = o;
}

// ---------- bf16 MFMA GEMM, tile 128(M)x64(N), BK=64, dbuf: O = A @ B^T + bias ----------
// 4 waves in 2x2; wave does 64(M)x32(N) = 4x2 MFMA tiles.
// mode 0: O fp32 flat (M,1024). mode 1: O bf16; z<2 -> (b,h,s,d); z==2 -> (b,h,d,s).
__global__ __launch_bounds__(256)
void gemm12864(const short* __restrict__ A0, const short* __restrict__ A1, const short* __restrict__ A2,
               const short* __restrict__ B0, const short* __restrict__ B1, const short* __restrict__ B2,
               const float* __restrict__ c0, const float* __restrict__ c1, const float* __restrict__ c2,
               void* __restrict__ O0, void* __restrict__ O1, void* __restrict__ O2,
               int mode)
{
    __shared__ short ldsw[2 * 12288];   // [buf][A 128*64 | B 64*64]; epilogue reuses as Tls

    const int z = blockIdx.z;
    const short* A    = z == 0 ? A0 : (z == 1 ? A1 : A2);
    const short* Bm   = z == 0 ? B0 : (z == 1 ? B1 : B2);
    const float* bias = z == 0 ? c0 : (z == 1 ? c1 : c2);
    void*        O    = z == 0 ? O0 : (z == 1 ? O1 : O2);

    const int t = threadIdx.x;
    const int lane = t & 63, w = t >> 6;
    const int wr = w >> 1, wc = w & 1;            // wave 2x2: wr -> 64-row half, wc -> 32-col half
    const int quad = lane >> 4, cl = lane & 15;
    const int rowBase = blockIdx.y * 128;
    const int colBase = blockIdx.x * 64;
    const int gl = ((lane & 7) - (lane >> 3)) & 7;

    f32x4 acc[4][2];
#pragma unroll
    for (int i = 0; i < 4; ++i)
#pragma unroll
        for (int j = 0; j < 2; ++j) acc[i][j] = (f32x4){0.f, 0.f, 0.f, 0.f};

    const int rstage = w * 8 + (lane >> 3);
    const short* Ag = A  + (size_t)(rowBase + rstage) * 1024 + gl * 8;
    const short* Bg = Bm + (size_t)(colBase + rstage) * 1024 + gl * 8;

    // prologue: stage tile 0 into buf 0
    {
        short* Als = ldsw;
        short* Bls = ldsw + 8192;
#pragma unroll
        for (int i = 0; i < 4; ++i)
            async16(&Als[(i * 32 + w * 8) * 64], Ag + (size_t)i * 32 * 1024);
#pragma unroll
        for (int i = 0; i < 2; ++i)
            async16(&Bls[(i * 32 + w * 8) * 64], Bg + (size_t)i * 32 * 1024);
    }

    for (int it = 0; it < 16; ++it) {
        const int cur = it & 1;
        __syncthreads();                          // drains vmcnt -> buf[cur] valid
        if (it < 15) {
            short* Als = ldsw + (cur ^ 1) * 12288;
            short* Bls = Als + 8192;
            const int k0 = (it + 1) * 64;
#pragma unroll
            for (int i = 0; i < 4; ++i)
                async16(&Als[(i * 32 + w * 8) * 64], Ag + (size_t)i * 32 * 1024 + k0);
#pragma unroll
            for (int i = 0; i < 2; ++i)
                async16(&Bls[(i * 32 + w * 8) * 64], Bg + (size_t)i * 32 * 1024 + k0);
        }
        const short* Als = ldsw + cur * 12288;
        const short* Bls = Als + 8192;
#pragma unroll
        for (int kk = 0; kk < 2; ++kk) {
            bf16x8 a[4], b[2];
#pragma unroll
            for (int mi = 0; mi < 4; ++mi) {
                int r = wr * 64 + mi * 16 + cl;
                int s = (kk * 4 + quad + r) & 7;
                a[mi] = *(const bf16x8*)&Als[r * 64 + s * 8];
            }
#pragma unroll
            for (int ni = 0; ni < 2; ++ni) {
                int r = wc * 32 + ni * 16 + cl;
                int s = (kk * 4 + quad + r) & 7;
                b[ni] = *(const bf16x8*)&Bls[r * 64 + s * 8];
            }
#pragma unroll
            for (int mi = 0; mi < 4; ++mi)
#pragma unroll
                for (int ni = 0; ni < 2; ++ni)
                    acc[mi][ni] = __builtin_amdgcn_mfma_f32_16x16x32_bf16(
                        a[mi], b[ni], acc[mi][ni], 0, 0, 0);
        }
    }

    if (mode == 0) {
        // flat f32 (M,1024)
#pragma unroll
        for (int mi = 0; mi < 4; ++mi)
#pragma unroll
            for (int ni = 0; ni < 2; ++ni) {
                int col = colBase + wc * 32 + ni * 16 + cl;
                float bv = bias[col];
#pragma unroll
                for (int reg = 0; reg < 4; ++reg) {
                    int row = rowBase + wr * 64 + mi * 16 + quad * 4 + reg;
                    ((float*)O)[(size_t)row * 1024 + col] = acc[mi][ni][reg] + bv;
                }
            }
        return;
    }

    __syncthreads();                              // staging reads done before Tls reuse
    short* Tls = ldsw;
    if (z == 2) {
        // vt (b,h,d,s): Tls[64][136]
#pragma unroll
        for (int mi = 0; mi < 4; ++mi)
#pragma unroll
            for (int ni = 0; ni < 2; ++ni) {
                int d = wc * 32 + ni * 16 + cl;
                float bv = bias[colBase + d];
                short4 pk;
                pk.x = f2bf(acc[mi][ni][0] + bv);
                pk.y = f2bf(acc[mi][ni][1] + bv);
                pk.z = f2bf(acc[mi][ni][2] + bv);
                pk.w = f2bf(acc[mi][ni][3] + bv);
                int sl = wr * 64 + mi * 16 + quad * 4;
                *(short4*)&Tls[d * 136 + sl] = pk;
            }
        __syncthreads();
        int d = t >> 2, s0 = (t & 3) * 32;
        int bb = rowBase >> 9, sBase = rowBase & 511, hh = colBase >> 6;
        short* dst = (short*)O + (((size_t)(bb * 16 + hh) * 64 + d) << 9) + sBase + s0;
#pragma unroll
        for (int j = 0; j < 4; ++j)
            *(bf16x8*)(dst + j * 8) = *(const bf16x8*)&Tls[d * 136 + s0 + j * 8];
    } else {
        // bhsd: Tls[128][72] (one head: colBase is 64-aligned, N=64)
#pragma unroll
        for (int mi = 0; mi < 4; ++mi)
#pragma unroll
            for (int ni = 0; ni < 2; ++ni) {
                int d = wc * 32 + ni * 16 + cl;
                float bv = bias[colBase + d];
#pragma unroll
                for (int reg = 0; reg < 4; ++reg) {
                    int sl = wr * 64 + mi * 16 + quad * 4 + reg;
                    Tls[sl * 72 + d] = f2bf(acc[mi][ni][reg] + bv);
                }
            }
        __syncthreads();
        int sl = t >> 1, half = t & 1;
        int bb = rowBase >> 9, sBase = rowBase & 511, hh = colBase >> 6;
        short* dst = (short*)O + (((size_t)(bb * 16 + hh) * 512 + sBase + sl) << 6) + half * 32;
#pragma unroll
        for (int j = 0; j < 4; ++j)
            *(bf16x8*)(dst + j * 8) = *(const bf16x8*)&Tls[sl * 72 + half * 32 + j * 8];
    }
}

// ---------------- Attention: single-wave workgroups, zero barriers ----------------
// block = one 64-thread wave = (b,h, 16-query tile) x all 512 keys.
// All LDS wave-private: qwr f32[16][68] | bins f32[16][68] | Pst short[16][72]
// (binsBf aliases Pst after the K-loop). In-wave LDS ordering via lgkmcnt only.
// Grid swizzle: bh = bid & 63 so same-bh blocks share an XCD (bid%8 = bh%8).
#define AT_BINS 4352
#define AT_PST  8704
#define AT_TOT  11264

__global__ __launch_bounds__(64)
void attn_kernel(const short* __restrict__ qg, const short* __restrict__ kg,
                 const short* __restrict__ vtg, const int* __restrict__ mask,
                 const float* __restrict__ relk, const float* __restrict__ relv,
                 short* __restrict__ attn_b)
{
    __shared__ __align__(16) char pool[AT_TOT];
    float* qwr    = (float*)pool;
    float* bins   = (float*)(pool + AT_BINS);
    short* Pst    = (short*)(pool + AT_PST);
    short* binsBf = Pst;                       // aliases Pst after K-loop (Pst dead)

    const int lane = threadIdx.x;
    const int quad = lane >> 4, cl = lane & 15;
    const int bid = blockIdx.x;
    const int bh = bid & 63, qbk = bid >> 6;   // XCD-friendly: bh%8 fixes XCD
    const int b = bh >> 4, h = bh & 15, q0 = qbk * 16;

    const short* qbase = qg  + ((size_t)bh * 512 + q0) * 64;
    const short* kbase = kg  + (size_t)bh * 512 * 64;
    const short* vbase = vtg + (size_t)bh * 64 * 512;
    const int*   mb    = mask + (size_t)b * 512 * 512 + (size_t)q0 * 512;

    // zero bins
    for (int i = lane; i < 16 * 68; i += 64) bins[i] = 0.f;

    // Q A-fragments direct from global
    bf16x8 qa0 = *(const bf16x8*)(qbase + cl * 64 + quad * 8);
    bf16x8 qa1 = *(const bf16x8*)(qbase + cl * 64 + 32 + quad * 8);

    // qrel: all 4 r-tiles (wave-private)
#pragma unroll
    for (int rt = 0; rt < 4; ++rt) {
        const float* kp = relk + (size_t)(rt * 16 + cl) * 64 + quad * 8;
        bf16x8 rb0, rb1;
#pragma unroll
        for (int j = 0; j < 8; ++j) rb0[j] = f2bf(kp[j]);
#pragma unroll
        for (int j = 0; j < 8; ++j) rb1[j] = f2bf(kp[32 + j]);
        f32x4 qr = (f32x4){0.f, 0.f, 0.f, 0.f};
        qr = __builtin_amdgcn_mfma_f32_16x16x32_bf16(qa0, rb0, qr, 0, 0, 0);
        qr = __builtin_amdgcn_mfma_f32_16x16x32_bf16(qa1, rb1, qr, 0, 0, 0);
#pragma unroll
        for (int reg = 0; reg < 4; ++reg)
            qwr[(quad * 4 + reg) * 68 + rt * 16 + cl] = qr[reg];
    }

    // ---- K-loop: 8 chunks of 64 keys, barrier-free, cross-chunk pipelineable ----
    f32x4 oacc[4];
#pragma unroll
    for (int dt = 0; dt < 4; ++dt) oacc[dt] = (f32x4){0.f, 0.f, 0.f, 0.f};
    float lpart[4] = {0.f, 0.f, 0.f, 0.f};

    for (int c = 0; c < 8; ++c) {
        const int k0 = c * 64;
#pragma unroll
        for (int nt = 0; nt < 4; ++nt) {
            const int kidx = k0 + nt * 16 + cl;
            const short* kp = kbase + (size_t)kidx * 64 + quad * 8;
            bf16x8 kb0 = *(const bf16x8*)kp;
            bf16x8 kb1 = *(const bf16x8*)(kp + 32);
            f32x4 s = (f32x4){0.f, 0.f, 0.f, 0.f};
            s = __builtin_amdgcn_mfma_f32_16x16x32_bf16(qa0, kb0, s, 0, 0, 0);
            s = __builtin_amdgcn_mfma_f32_16x16x32_bf16(qa1, kb1, s, 0, 0, 0);
#pragma unroll
            for (int reg = 0; reg < 4; ++reg) {
                int q = quad * 4 + reg;
                int id = mb[q * 512 + kidx];
                float sc = (s[reg] + 0.25f * qwr[q * 68 + id]) * 0.125f;
                float p = (id == 0) ? 0.f : __expf(sc);   // no-max softmax; masked -> 0
                lpart[reg] += p;
                atomicAdd(&bins[q * 68 + id], p);
                Pst[q * 72 + nt * 16 + cl] = f2bf(p);
            }
        }
        // P C-layout -> A-layout via wave-private LDS (in-wave RAW)
        bf16x8 pa0 = *(const bf16x8*)&Pst[cl * 72 + quad * 8];
        bf16x8 pa1 = *(const bf16x8*)&Pst[cl * 72 + 32 + quad * 8];
#pragma unroll
        for (int dt = 0; dt < 4; ++dt) {
            const short* vp = vbase + (size_t)(dt * 16 + cl) * 512 + k0 + quad * 8;
            bf16x8 vb0 = *(const bf16x8*)vp;
            bf16x8 vb1 = *(const bf16x8*)(vp + 32);
            oacc[dt] = __builtin_amdgcn_mfma_f32_16x16x32_bf16(pa0, vb0, oacc[dt], 0, 0, 0);
            oacc[dt] = __builtin_amdgcn_mfma_f32_16x16x32_bf16(pa1, vb1, oacc[dt], 0, 0, 0);
        }
    }

    // per-q softmax denominators, in-register (16-lane groups share q)
    float invq[4];
#pragma unroll
    for (int reg = 0; reg < 4; ++reg) {
        float l = lpart[reg];
#pragma unroll
        for (int m = 8; m >= 1; m >>= 1) l += __shfl_xor(l, m);
        invq[reg] = 1.0f / l;
    }

    // bins -> bf16 into binsBf (aliases Pst; in-wave ordering)
    {
        int q = lane >> 2, r0 = (lane & 3) * 16;
#pragma unroll
        for (int j = 0; j < 4; ++j) {
            float4 f = *(const float4*)&bins[q * 68 + r0 + j * 4];
            short4 o;
            o.x = f2bf(f.x); o.y = f2bf(f.y); o.z = f2bf(f.z); o.w = f2bf(f.w);
            *(short4*)&binsBf[q * 72 + r0 + j * 4] = o;
        }
    }

    // rel_out = bins @ relv, all 4 d-tiles; combine + normalize + store
    bf16x8 ba0 = *(const bf16x8*)&binsBf[cl * 72 + quad * 8];
    bf16x8 ba1 = *(const bf16x8*)&binsBf[cl * 72 + 32 + quad * 8];
#pragma unroll
    for (int dt = 0; dt < 4; ++dt) {
        const float* rp = relv + (size_t)(quad * 8) * 64 + dt * 16 + cl;
        bf16x8 rv0, rv1;
#pragma unroll
        for (int j = 0; j < 8; ++j) rv0[j] = f2bf(rp[j * 64]);
#pragma unroll
        for (int j = 0; j < 8; ++j) rv1[j] = f2bf(rp[2048 + j * 64]);
        f32x4 racc = (f32x4){0.f, 0.f, 0.f, 0.f};
        racc = __builtin_amdgcn_mfma_f32_16x16x32_bf16(ba0, rv0, racc, 0, 0, 0);
        racc = __builtin_amdgcn_mfma_f32_16x16x32_bf16(ba1, rv1, racc, 0, 0, 0);
#pragma unroll
        for (int reg = 0; reg < 4; ++reg) {
            int q = quad * 4 + reg;
            float val = (oacc[dt][reg] + 0.25f * racc[reg]) * invq[reg];
            attn_b[(size_t)(b * 512 + q0 + q) * 1024 + h * 64 + dt * 16 + cl] = f2bf(val);
        }
    }
}

extern "C" void kernel_launch(void* const* d_in, const int* in_sizes, int n_in,
                              void* d_out, int out_size, void* d_ws, size_t ws_size,
                              hipStream_t stream)
{
    const float* q_in = (const float*)d_in[0];
    const float* k_in = (const float*)d_in[1];
    const float* v_in = (const float*)d_in[2];
    const int*   mask = (const int*)d_in[3];
    const float* Wq   = (const float*)d_in[4];
    const float* bq   = (const float*)d_in[5];
    const float* Wk   = (const float*)d_in[6];
    const float* bk   = (const float*)d_in[7];
    const float* Wv   = (const float*)d_in[8];
    const float* bv   = (const float*)d_in[9];
    const float* Wo   = (const float*)d_in[10];
    const float* bo   = (const float*)d_in[11];
    const float* relk = (const float*)d_in[12];
    const float* relv = (const float*)d_in[13];

    char* ws = (char*)d_ws;
    short* qb     = (short*)(ws);                  // 4MB
    short* kb     = (short*)(ws + (4u  << 20));    // 4MB
    short* vt     = (short*)(ws + (8u  << 20));    // 4MB
    short* attn_b = (short*)(ws + (12u << 20));    // 4MB
    short* Xq     = (short*)(ws + (16u << 20));    // 4MB
    short* Xk     = (short*)(ws + (20u << 20));
    short* Xv     = (short*)(ws + (24u << 20));
    short* Wqb    = (short*)(ws + (28u << 20));    // 2MB
    short* Wkb    = (short*)(ws + (30u << 20));
    short* Wvb    = (short*)(ws + (32u << 20));
    short* Wob    = (short*)(ws + (34u << 20));

    cast_all<<<10240, 256, 0, stream>>>(q_in, k_in, v_in, Wq, Wk, Wv, Wo,
                                        Xq, Xk, Xv, Wqb, Wkb, Wvb, Wob);

    gemm12864<<<dim3(16, 16, 3), 256, 0, stream>>>(
        Xq, Xk, Xv, Wqb, Wkb, Wvb, bq, bk, bv, qb, kb, vt, 1);

    attn_kernel<<<dim3(2048), 64, 0, stream>>>(qb, kb, vt, mask, relk, relv, attn_b);

    gemm12864<<<dim3(16, 16, 1), 256, 0, stream>>>(
        attn_b, attn_b, attn_b, Wob, Wob, Wob, bo, bo, bo,
        (void*)d_out, (void*)d_out, (void*)d_out, 0);
}